// Round 13
// baseline (488.534 us; speedup 1.0000x reference)
//
#include <hip/hip_runtime.h>
#include <hip/hip_bf16.h>

// 3-layer GCN: bf16-MFMA GEMMs + degree-sorted CSR gather-reduce.
//   hs = bf16( dinv[row] * (act(A) @ W) )     (MFMA GEMM, act = BN+ReLU fused)
//   y[i] = dinv[i]*(hs[i] + sum_{e: s->i} hs[s]) + b  (fp32 acc, bf16 out)
// Aggregate ledger (r3-r11): L3-latency bound (FETCH 93MB = ~69% L2 miss of
// 12.8MB hs, matches 4MB/XCD model); only chain interleaving moves time
// (2->4->8 chains: 115->100->93us). r12: grid 512->1024 (r4's regression was
// confounded) + software-pipelined index prefetch (idx latency hidden under
// row-load wait). GEMM/prep identical to r11.

typedef __attribute__((ext_vector_type(8))) short short8;   // 8 bf16
typedef __attribute__((ext_vector_type(4))) float f32x4;    // 4 fp32 acc

__device__ inline unsigned short f2bf(float f) {  // round-to-nearest-even
    unsigned int u = __float_as_uint(f);
    return (unsigned short)((u + 0x7fff + ((u >> 16) & 1)) >> 16);
}
__device__ inline float bf2f_lo(unsigned int p) { return __uint_as_float(p << 16); }
__device__ inline float bf2f_hi(unsigned int p) { return __uint_as_float(p & 0xffff0000u); }

__device__ inline void bf4_acc(uint2 v, float* a) {
    a[0] += bf2f_lo(v.x); a[1] += bf2f_hi(v.x);
    a[2] += bf2f_lo(v.y); a[3] += bf2f_hi(v.y);
}

// ---- fused prep: count_deg (atomics into deg) + x->bf16 + W->Wt bf16 ----
__global__ void prep_kernel(const int* __restrict__ dst, int E,
                            int* __restrict__ deg,
                            const float* __restrict__ x,
                            unsigned short* __restrict__ xb, int total4,
                            const float* __restrict__ W1,
                            const float* __restrict__ W2,
                            const float* __restrict__ W3,
                            unsigned short* __restrict__ wt1,
                            unsigned short* __restrict__ wt2,
                            unsigned short* __restrict__ wt3,
                            int EB, int XB) {
    const int b = blockIdx.x;
    const int t = threadIdx.x;
    if (b < EB) {
        int e = b * 256 + t;
        if (e < E) atomicAdd(deg + dst[e], 1);
    } else if (b < EB + XB) {
        int i = (b - EB) * 256 + t;
        if (i < total4) {
            float4 v = reinterpret_cast<const float4*>(x)[i];
            uint2 p;
            p.x = f2bf(v.x) | ((unsigned)f2bf(v.y) << 16);
            p.y = f2bf(v.z) | ((unsigned)f2bf(v.w) << 16);
            reinterpret_cast<uint2*>(xb)[i] = p;
        }
    } else if (b < EB + XB + 64) {
        int idx = (b - EB - XB) * 256 + t;   // 128x128
        int k = idx >> 7, nn = idx & 127;
        wt1[nn * 128 + k] = f2bf(W1[idx]);
    } else if (b < EB + XB + 128) {
        int idx = (b - EB - XB - 64) * 256 + t;
        int k = idx >> 7, nn = idx & 127;
        wt2[nn * 128 + k] = f2bf(W2[idx]);
    } else {
        int idx = (b - EB - XB - 128) * 256 + t;  // 128x64
        int k = idx >> 6, nn = idx & 63;
        wt3[nn * 128 + k] = f2bf(W3[idx]);
    }
}

// ---- fused: dinv + degree histogram + per-chunk rowptr prefix ----
__global__ __launch_bounds__(256) void prescan_kernel(
    const int* __restrict__ deg, int n, int B, float* __restrict__ dinv,
    int* __restrict__ bh, int* __restrict__ rowptr, int* __restrict__ bsum) {
    __shared__ int lh[64];
    __shared__ int sh[256];
    const int t = threadIdx.x, b = blockIdx.x;
    if (t < 64) lh[t] = 0;
    __syncthreads();
    const int base = b * 2048 + t * 8;
    int v[8];
    int run = 0;
#pragma unroll
    for (int j = 0; j < 8; ++j) {
        int idx = base + j;
        int d = 0;
        if (idx < n) {
            d = deg[idx];
            dinv[idx] = rsqrtf((float)(d + 1));
            atomicAdd(&lh[min(d, 63)], 1);
        }
        run += d;
        v[j] = run;
    }
    sh[t] = run;
    __syncthreads();
#pragma unroll
    for (int off = 1; off < 256; off <<= 1) {
        int add = (t >= off) ? sh[t - off] : 0;
        __syncthreads();
        sh[t] += add;
        __syncthreads();
    }
    int prev = (t > 0) ? sh[t - 1] : 0;
#pragma unroll
    for (int j = 0; j < 8; ++j) {
        int idx = base + j;
        if (idx < n) rowptr[idx + 1] = v[j] + prev;
    }
    if (t == 255) bsum[b] = sh[255];
    if (b == 0 && t == 0) rowptr[0] = 0;
    if (t < 64) bh[t * B + b] = lh[t];
}

// ---- fused single-block: excl scan bh[64*B] + incl scan bsum[B] ----
__global__ void midscan_kernel(int* __restrict__ bh, int totalbh,
                               int* __restrict__ bsum, int B) {
    __shared__ int sh[256];
    const int t = threadIdx.x;
    int base = 0;
    for (int start = 0; start < totalbh; start += 256) {
        int i = start + t;
        int v = (i < totalbh) ? bh[i] : 0;
        sh[t] = v;
        __syncthreads();
#pragma unroll
        for (int off = 1; off < 256; off <<= 1) {
            int add = (t >= off) ? sh[t - off] : 0;
            __syncthreads();
            sh[t] += add;
            __syncthreads();
        }
        int excl = (t > 0 ? sh[t - 1] : 0) + base;
        if (i < totalbh) bh[i] = excl;
        base += sh[255];
        __syncthreads();
    }
    int v = (t < B) ? bsum[t] : 0;
    sh[t] = v;
    __syncthreads();
#pragma unroll
    for (int off = 1; off < 64; off <<= 1) {
        int add = (t >= off && t < 64) ? sh[t - off] : 0;
        __syncthreads();
        if (t < 64) sh[t] += add;
        __syncthreads();
    }
    if (t < B) bsum[t] = sh[t];
}

// ---- fused: place (blocks 0..B-1) + rowptr chunk-offset add (B..2B-1) ----
__global__ void place_scanC_kernel(const int* __restrict__ deg, int n, int B,
                                   const int* __restrict__ bh,
                                   const int* __restrict__ bsum,
                                   int* __restrict__ perm,
                                   int* __restrict__ rowptr) {
    const int t = threadIdx.x;
    if ((int)blockIdx.x < B) {
        const int b = blockIdx.x;
        __shared__ int lbase[64];
        __shared__ int lcur[64];
        if (t < 64) {
            lbase[t] = bh[t * B + b];
            lcur[t] = 0;
        }
        __syncthreads();
        const int lim = min((b + 1) * 2048, n);
        for (int i = b * 2048 + t; i < lim; i += 256) {
            int d = min(deg[i], 63);
            int r = atomicAdd(&lcur[d], 1);
            perm[lbase[d] + r] = i;
        }
    } else {
        const int c = blockIdx.x - B;
        if (c == 0) return;
        const int off = bsum[c - 1];
        const int lim = min((c + 1) * 2048, n);
        for (int i = c * 2048 + t; i < lim; i += 256) rowptr[i + 1] += off;
    }
}

// destructive cursor CSR edge placement
__global__ void csr_build_kernel(const int* __restrict__ src,
                                 const int* __restrict__ dst, int E,
                                 int* __restrict__ rowptr,
                                 int* __restrict__ csr_src) {
    int e = blockIdx.x * blockDim.x + threadIdx.x;
    if (e < E) {
        int pos = atomicAdd(rowptr + dst[e], 1);
        csr_src[pos] = src[e];
    }
}

// C[n x NC] = bf16( dinv[row] * (act(A[n x 128]) @ W) ); BN finalize folded in.
template <int NC, bool BN>
__global__ __launch_bounds__(256) void gemm_mfma(
    const unsigned short* __restrict__ A, const unsigned short* __restrict__ Wt,
    unsigned short* __restrict__ C, int n, const float* __restrict__ stats,
    const float* __restrict__ g, const float* __restrict__ be, float invn,
    const float* __restrict__ dinv) {
    __shared__ unsigned short Asd[64][136];   // +8 pad: 2-way bank (free)
    __shared__ unsigned short Bsd[NC][136];
    __shared__ float ssl[256];
    const int tid = threadIdx.x;
    const int wave = tid >> 6;
    const int lane = tid & 63;
    const int row0 = blockIdx.x * 64;

    if (BN) {
        if (tid < 128) {
            float mean = stats[tid] * invn;
            float var = fmaf(-mean, mean, stats[128 + tid] * invn);
            float sc = g[tid] * rsqrtf(var + 1e-5f);
            ssl[tid] = sc;
            ssl[128 + tid] = fmaf(-mean, sc, be[tid]);
        }
        __syncthreads();
    }

    for (int idx = tid; idx < NC * 16; idx += 256) {
        int r = idx >> 4;
        int c = (idx & 15) * 8;
        uint4 v = *reinterpret_cast<const uint4*>(Wt + r * 128 + c);
        *reinterpret_cast<uint4*>(&Bsd[r][c]) = v;
    }
    for (int idx = tid; idx < 64 * 16; idx += 256) {
        int r = idx >> 4;
        int c = (idx & 15) * 8;
        int grow = row0 + r;
        uint4 v = make_uint4(0u, 0u, 0u, 0u);
        if (grow < n)
            v = *reinterpret_cast<const uint4*>(A + (size_t)grow * 128 + c);
        if (BN) {
            unsigned int p[4] = {v.x, v.y, v.z, v.w};
#pragma unroll
            for (int h = 0; h < 4; ++h) {
                int f = c + h * 2;
                float lo = fmaxf(fmaf(bf2f_lo(p[h]), ssl[f], ssl[128 + f]), 0.f);
                float hi = fmaxf(fmaf(bf2f_hi(p[h]), ssl[f + 1], ssl[129 + f]), 0.f);
                p[h] = f2bf(lo) | ((unsigned)f2bf(hi) << 16);
            }
            v = make_uint4(p[0], p[1], p[2], p[3]);
        }
        *reinterpret_cast<uint4*>(&Asd[r][c]) = v;
    }
    __syncthreads();

    f32x4 acc[NC / 16];
#pragma unroll
    for (int t = 0; t < NC / 16; ++t) acc[t] = (f32x4)(0.f);

    const int l15 = lane & 15;
    const int quad = lane >> 4;
#pragma unroll
    for (int kb = 0; kb < 128; kb += 32) {
        short8 a = *reinterpret_cast<const short8*>(&Asd[wave * 16 + l15][kb + quad * 8]);
#pragma unroll
        for (int t = 0; t < NC / 16; ++t) {
            short8 b = *reinterpret_cast<const short8*>(&Bsd[t * 16 + l15][kb + quad * 8]);
            acc[t] = __builtin_amdgcn_mfma_f32_16x16x32_bf16(a, b, acc[t], 0, 0, 0);
        }
    }

    const int rbase = row0 + wave * 16 + quad * 4;
    float dv[4] = {0.f, 0.f, 0.f, 0.f};
    if (rbase < n) {  // dinv padded by +64 in ws
        float4 d4 = *reinterpret_cast<const float4*>(dinv + rbase);
        dv[0] = d4.x; dv[1] = d4.y; dv[2] = d4.z; dv[3] = d4.w;
    }
#pragma unroll
    for (int t = 0; t < NC / 16; ++t) {
        int col = t * 16 + l15;
#pragma unroll
        for (int r = 0; r < 4; ++r) {
            int row = rbase + r;
            if (row < n)
                C[(size_t)row * NC + col] = f2bf(acc[t][r] * dv[r]);
        }
    }
}

// Degree-sorted 4-node gather-reduce with software-pipelined index prefetch:
// indices for iteration k+1 are loaded before iteration k's rows are
// consumed, hiding index latency under the row-load wait.
template <int F, bool STATS, bool OBF>
__global__ __launch_bounds__(256) void aggregate_kernel(
    const unsigned short* __restrict__ hs, const int* __restrict__ csr_src,
    const int* __restrict__ rowptr, const int* __restrict__ perm,
    const float* __restrict__ dinv, const float* __restrict__ bias,
    void* __restrict__ outp, int n, float* __restrict__ stats) {
    const int LANES = F / 4;            // 32 for F=128, 16 for F=64
    const int GROUPS = 256 / LANES;
    const int lane = threadIdx.x % LANES;
    const int grp = threadIdx.x / LANES;
    const int fq = lane * 4;
    const float4 b4 = *reinterpret_cast<const float4*>(bias + fq);
    float s[4] = {}, sq[4] = {};

    const int stride = gridDim.x * GROUPS * 4;

    for (int j0 = (blockIdx.x * GROUPS + grp) * 4; j0 < n; j0 += stride) {
        const int nv = min(4, n - j0);
        int nd[4], e[4], end[4];
        float acc[4][4] = {};
#pragma unroll
        for (int q = 0; q < 4; ++q) {
            if (q < nv) {
                int node = perm[j0 + q];
                nd[q] = node;
                e[q] = (node == 0) ? 0 : rowptr[node - 1];
                end[q] = rowptr[node];
            } else {
                nd[q] = -1; e[q] = 0; end[q] = 0;
            }
        }
#pragma unroll
        for (int q = 0; q < 4; ++q)
            if (nd[q] >= 0)
                bf4_acc(*reinterpret_cast<const uint2*>(hs + (size_t)nd[q] * F + fq), acc[q]);
        int rem = end[0] - e[0];
#pragma unroll
        for (int q = 1; q < 4; ++q)
            if (q < nv) rem = min(rem, end[q] - e[q]);

        int i0[4], i1[4];
        if (rem >= 2) {                 // prologue: indices for iter 0
#pragma unroll
            for (int q = 0; q < 4; ++q) {
                i0[q] = csr_src[e[q]];
                i1[q] = csr_src[e[q] + 1];
                e[q] += 2;
            }
        }
        while (rem >= 2) {
            uint2 v0[4], v1[4];
#pragma unroll
            for (int q = 0; q < 4; ++q) {
                v0[q] = *reinterpret_cast<const uint2*>(hs + (size_t)i0[q] * F + fq);
                v1[q] = *reinterpret_cast<const uint2*>(hs + (size_t)i1[q] * F + fq);
            }
            rem -= 2;
            if (rem >= 2) {             // prefetch next indices before acc
#pragma unroll
                for (int q = 0; q < 4; ++q) {
                    i0[q] = csr_src[e[q]];
                    i1[q] = csr_src[e[q] + 1];
                    e[q] += 2;
                }
            }
#pragma unroll
            for (int q = 0; q < 4; ++q) {
                bf4_acc(v0[q], acc[q]);
                bf4_acc(v1[q], acc[q]);
            }
        }
        // tails (tiny after degree sort)
#pragma unroll
        for (int q = 0; q < 4; ++q) {
            for (; e[q] < end[q]; ++e[q]) {
                int s0 = csr_src[e[q]];
                bf4_acc(*reinterpret_cast<const uint2*>(hs + (size_t)s0 * F + fq), acc[q]);
            }
        }
#pragma unroll
        for (int q = 0; q < 4; ++q) {
            if (nd[q] < 0) continue;
            const float di = dinv[nd[q]];
            float y[4];
            y[0] = fmaf(di, acc[q][0], b4.x);
            y[1] = fmaf(di, acc[q][1], b4.y);
            y[2] = fmaf(di, acc[q][2], b4.z);
            y[3] = fmaf(di, acc[q][3], b4.w);
            if (OBF) {
                uint2 p;
                p.x = f2bf(y[0]) | ((unsigned)f2bf(y[1]) << 16);
                p.y = f2bf(y[2]) | ((unsigned)f2bf(y[3]) << 16);
                *reinterpret_cast<uint2*>((unsigned short*)outp + (size_t)nd[q] * F + fq) = p;
            } else {
                *reinterpret_cast<float4*>((float*)outp + (size_t)nd[q] * F + fq) =
                    make_float4(y[0], y[1], y[2], y[3]);
            }
            if (STATS) {
#pragma unroll
                for (int j = 0; j < 4; ++j) {
                    s[j] += y[j];
                    sq[j] = fmaf(y[j], y[j], sq[j]);
                }
            }
        }
    }

    if (STATS) {  // F=128 shape: LANES=32, GROUPS=8
        __shared__ float sred[32][8];
#pragma unroll
        for (int q = 0; q < 8; ++q) {
            float v = (q < 4) ? s[q] : sq[q - 4];
            sred[lane][grp] = v;
            __syncthreads();
            if (grp == 0) {
                float t = 0.f;
#pragma unroll
                for (int g = 0; g < 8; ++g) t += sred[lane][g];
                int f = fq + (q & 3);
                atomicAdd(stats + ((q < 4) ? f : 128 + f), t);
            }
            __syncthreads();
        }
    }
}

extern "C" void kernel_launch(void* const* d_in, const int* in_sizes, int n_in,
                              void* d_out, int out_size, void* d_ws,
                              size_t ws_size, hipStream_t stream) {
    const float* x   = (const float*)d_in[0];
    const int*   ei  = (const int*)d_in[1];
    const float* W1  = (const float*)d_in[2];
    const float* b1  = (const float*)d_in[3];
    const float* g1  = (const float*)d_in[4];
    const float* be1 = (const float*)d_in[5];
    const float* W2  = (const float*)d_in[6];
    const float* b2  = (const float*)d_in[7];
    const float* g2  = (const float*)d_in[8];
    const float* be2 = (const float*)d_in[9];
    const float* W3  = (const float*)d_in[10];
    const float* b3  = (const float*)d_in[11];
    float* out = (float*)d_out;

    const int n = in_sizes[0] / 128;
    const int E = in_sizes[1] / 2;
    const int* src = ei;
    const int* dst = ei + E;

    const int B = (n + 2047) / 2048;             // sort/scan chunks (25)

    float* wsf    = (float*)d_ws;
    float* stats1 = wsf;                         // 256
    float* stats2 = stats1 + 256;                // 256
    int*   deg    = (int*)(stats2 + 256);        // n
    float* dinv   = (float*)(deg + n);           // n + 64 (padded)
    int*   bh     = (int*)(dinv + n + 64);       // 64*B (<= 64*32)
    int*   bsum   = bh + 64 * 32;                // 64
    int*   rowptr = bsum + 64;                   // n+1
    int*   perm   = rowptr + (n + 1);            // n
    int*   csrsrc = perm + n;                    // E
    unsigned short* wt1 = (unsigned short*)(csrsrc + E);      // 128*128
    unsigned short* wt2 = wt1 + 128 * 128;                    // 128*128
    unsigned short* wt3 = wt2 + 128 * 128;                    // 64*128
    unsigned short* abuf = wt3 + 64 * 128;                    // n*128 bf16
    unsigned short* hsb  = abuf + (size_t)n * 128;            // n*128 bf16

    const int EB = (E + 255) / 256;
    const int total4 = n * 32;
    const int XB = (total4 + 255) / 256;

    hipMemsetAsync(wsf, 0, (size_t)(512 + n) * 4, stream);
    prep_kernel<<<EB + XB + 160, 256, 0, stream>>>(dst, E, deg, x, abuf, total4,
                                                   W1, W2, W3, wt1, wt2, wt3,
                                                   EB, XB);
    prescan_kernel<<<B, 256, 0, stream>>>(deg, n, B, dinv, bh, rowptr, bsum);
    midscan_kernel<<<1, 256, 0, stream>>>(bh, 64 * B, bsum, B);
    place_scanC_kernel<<<2 * B, 256, 0, stream>>>(deg, n, B, bh, bsum, perm, rowptr);
    csr_build_kernel<<<EB, 256, 0, stream>>>(src, dst, E, rowptr, csrsrc);

    const int gemmGrid = (n + 63) / 64;
    const int aggGrid = 1024;                    // r12: 2x grid (MLP lever)
    const float invn = 1.0f / n;

    // ---- layer 1 ----
    gemm_mfma<128, false><<<gemmGrid, 256, 0, stream>>>(abuf, wt1, hsb, n, nullptr, nullptr, nullptr, invn, dinv);
    aggregate_kernel<128, true, true><<<aggGrid, 256, 0, stream>>>(hsb, csrsrc, rowptr, perm, dinv, b1, abuf, n, stats1);
    // ---- layer 2 ----
    gemm_mfma<128, true><<<gemmGrid, 256, 0, stream>>>(abuf, wt2, hsb, n, stats1, g1, be1, invn, dinv);
    aggregate_kernel<128, true, true><<<aggGrid, 256, 0, stream>>>(hsb, csrsrc, rowptr, perm, dinv, b2, abuf, n, stats2);
    // ---- layer 3 ----
    gemm_mfma<64, true><<<gemmGrid, 256, 0, stream>>>(abuf, wt3, hsb, n, stats2, g2, be2, invn, dinv);
    aggregate_kernel<64, false, false><<<aggGrid, 256, 0, stream>>>(hsb, csrsrc, rowptr, perm, dinv, b3, out, n, nullptr);
}

// Round 14
// 425.285 us; speedup vs baseline: 1.1487x; 1.1487x over previous
//
#include <hip/hip_runtime.h>
#include <hip/hip_bf16.h>

// 3-layer GCN: bf16-MFMA GEMMs + degree-sorted CSR gather-reduce.
//   hs = bf16( dinv[row] * (act(A) @ W) )     (MFMA GEMM, act = BN+ReLU fused)
//   y[i] = dinv[i]*(hs[i] + sum_{e: s->i} hs[s]) + b  (fp32 acc, bf16 out)
// Aggregate ledger (r3-r13): ~93us/F128-layer plateau at 512 blk / 4-node /
// x2 unroll. Concurrency beyond that REGRESSES (r4 2x grid, r7 4-chain,
// r13 2x grid + prefetch: 93->121us despite occupancy 13->25%) — congestion
// on the L2-miss path. Bytes (r5) and transactions (r7) are no-ops.
// r14: aggregate reverted to r11 exact config; GEMM split to 64-col blocks
// (LDS 52->36KB, 2->4 blk/CU) for staging overlap.

typedef __attribute__((ext_vector_type(8))) short short8;   // 8 bf16
typedef __attribute__((ext_vector_type(4))) float f32x4;    // 4 fp32 acc

__device__ inline unsigned short f2bf(float f) {  // round-to-nearest-even
    unsigned int u = __float_as_uint(f);
    return (unsigned short)((u + 0x7fff + ((u >> 16) & 1)) >> 16);
}
__device__ inline float bf2f_lo(unsigned int p) { return __uint_as_float(p << 16); }
__device__ inline float bf2f_hi(unsigned int p) { return __uint_as_float(p & 0xffff0000u); }

__device__ inline void bf4_acc(uint2 v, float* a) {
    a[0] += bf2f_lo(v.x); a[1] += bf2f_hi(v.x);
    a[2] += bf2f_lo(v.y); a[3] += bf2f_hi(v.y);
}

// ---- fused prep: count_deg (atomics into deg) + x->bf16 + W->Wt bf16 ----
__global__ void prep_kernel(const int* __restrict__ dst, int E,
                            int* __restrict__ deg,
                            const float* __restrict__ x,
                            unsigned short* __restrict__ xb, int total4,
                            const float* __restrict__ W1,
                            const float* __restrict__ W2,
                            const float* __restrict__ W3,
                            unsigned short* __restrict__ wt1,
                            unsigned short* __restrict__ wt2,
                            unsigned short* __restrict__ wt3,
                            int EB, int XB) {
    const int b = blockIdx.x;
    const int t = threadIdx.x;
    if (b < EB) {
        int e = b * 256 + t;
        if (e < E) atomicAdd(deg + dst[e], 1);
    } else if (b < EB + XB) {
        int i = (b - EB) * 256 + t;
        if (i < total4) {
            float4 v = reinterpret_cast<const float4*>(x)[i];
            uint2 p;
            p.x = f2bf(v.x) | ((unsigned)f2bf(v.y) << 16);
            p.y = f2bf(v.z) | ((unsigned)f2bf(v.w) << 16);
            reinterpret_cast<uint2*>(xb)[i] = p;
        }
    } else if (b < EB + XB + 64) {
        int idx = (b - EB - XB) * 256 + t;   // 128x128
        int k = idx >> 7, nn = idx & 127;
        wt1[nn * 128 + k] = f2bf(W1[idx]);
    } else if (b < EB + XB + 128) {
        int idx = (b - EB - XB - 64) * 256 + t;
        int k = idx >> 7, nn = idx & 127;
        wt2[nn * 128 + k] = f2bf(W2[idx]);
    } else {
        int idx = (b - EB - XB - 128) * 256 + t;  // 128x64
        int k = idx >> 6, nn = idx & 63;
        wt3[nn * 128 + k] = f2bf(W3[idx]);
    }
}

// ---- fused: dinv + degree histogram + per-chunk rowptr prefix ----
__global__ __launch_bounds__(256) void prescan_kernel(
    const int* __restrict__ deg, int n, int B, float* __restrict__ dinv,
    int* __restrict__ bh, int* __restrict__ rowptr, int* __restrict__ bsum) {
    __shared__ int lh[64];
    __shared__ int sh[256];
    const int t = threadIdx.x, b = blockIdx.x;
    if (t < 64) lh[t] = 0;
    __syncthreads();
    const int base = b * 2048 + t * 8;
    int v[8];
    int run = 0;
#pragma unroll
    for (int j = 0; j < 8; ++j) {
        int idx = base + j;
        int d = 0;
        if (idx < n) {
            d = deg[idx];
            dinv[idx] = rsqrtf((float)(d + 1));
            atomicAdd(&lh[min(d, 63)], 1);
        }
        run += d;
        v[j] = run;
    }
    sh[t] = run;
    __syncthreads();
#pragma unroll
    for (int off = 1; off < 256; off <<= 1) {
        int add = (t >= off) ? sh[t - off] : 0;
        __syncthreads();
        sh[t] += add;
        __syncthreads();
    }
    int prev = (t > 0) ? sh[t - 1] : 0;
#pragma unroll
    for (int j = 0; j < 8; ++j) {
        int idx = base + j;
        if (idx < n) rowptr[idx + 1] = v[j] + prev;
    }
    if (t == 255) bsum[b] = sh[255];
    if (b == 0 && t == 0) rowptr[0] = 0;
    if (t < 64) bh[t * B + b] = lh[t];
}

// ---- fused single-block: excl scan bh[64*B] + incl scan bsum[B] ----
__global__ void midscan_kernel(int* __restrict__ bh, int totalbh,
                               int* __restrict__ bsum, int B) {
    __shared__ int sh[256];
    const int t = threadIdx.x;
    int base = 0;
    for (int start = 0; start < totalbh; start += 256) {
        int i = start + t;
        int v = (i < totalbh) ? bh[i] : 0;
        sh[t] = v;
        __syncthreads();
#pragma unroll
        for (int off = 1; off < 256; off <<= 1) {
            int add = (t >= off) ? sh[t - off] : 0;
            __syncthreads();
            sh[t] += add;
            __syncthreads();
        }
        int excl = (t > 0 ? sh[t - 1] : 0) + base;
        if (i < totalbh) bh[i] = excl;
        base += sh[255];
        __syncthreads();
    }
    int v = (t < B) ? bsum[t] : 0;
    sh[t] = v;
    __syncthreads();
#pragma unroll
    for (int off = 1; off < 64; off <<= 1) {
        int add = (t >= off && t < 64) ? sh[t - off] : 0;
        __syncthreads();
        if (t < 64) sh[t] += add;
        __syncthreads();
    }
    if (t < B) bsum[t] = sh[t];
}

// ---- fused: place (blocks 0..B-1) + rowptr chunk-offset add (B..2B-1) ----
__global__ void place_scanC_kernel(const int* __restrict__ deg, int n, int B,
                                   const int* __restrict__ bh,
                                   const int* __restrict__ bsum,
                                   int* __restrict__ perm,
                                   int* __restrict__ rowptr) {
    const int t = threadIdx.x;
    if ((int)blockIdx.x < B) {
        const int b = blockIdx.x;
        __shared__ int lbase[64];
        __shared__ int lcur[64];
        if (t < 64) {
            lbase[t] = bh[t * B + b];
            lcur[t] = 0;
        }
        __syncthreads();
        const int lim = min((b + 1) * 2048, n);
        for (int i = b * 2048 + t; i < lim; i += 256) {
            int d = min(deg[i], 63);
            int r = atomicAdd(&lcur[d], 1);
            perm[lbase[d] + r] = i;
        }
    } else {
        const int c = blockIdx.x - B;
        if (c == 0) return;
        const int off = bsum[c - 1];
        const int lim = min((c + 1) * 2048, n);
        for (int i = c * 2048 + t; i < lim; i += 256) rowptr[i + 1] += off;
    }
}

// destructive cursor CSR edge placement
__global__ void csr_build_kernel(const int* __restrict__ src,
                                 const int* __restrict__ dst, int E,
                                 int* __restrict__ rowptr,
                                 int* __restrict__ csr_src) {
    int e = blockIdx.x * blockDim.x + threadIdx.x;
    if (e < E) {
        int pos = atomicAdd(rowptr + dst[e], 1);
        csr_src[pos] = src[e];
    }
}

// C[n x NC] = bf16( dinv[row] * (act(A[n x 128]) @ W) ); BN finalize folded.
// 64-row x 64-col blocks (grid.y = NC/64): LDS 36KB -> 4 blk/CU overlap.
template <int NC, bool BN>
__global__ __launch_bounds__(256) void gemm_mfma(
    const unsigned short* __restrict__ A, const unsigned short* __restrict__ Wt,
    unsigned short* __restrict__ C, int n, const float* __restrict__ stats,
    const float* __restrict__ g, const float* __restrict__ be, float invn,
    const float* __restrict__ dinv) {
    __shared__ unsigned short Asd[64][136];   // +8 pad: 2-way bank (free)
    __shared__ unsigned short Bsd[64][136];
    __shared__ float ssl[256];
    const int tid = threadIdx.x;
    const int wave = tid >> 6;
    const int lane = tid & 63;
    const int row0 = blockIdx.x * 64;
    const int col0 = blockIdx.y * 64;

    if (BN) {
        if (tid < 128) {
            float mean = stats[tid] * invn;
            float var = fmaf(-mean, mean, stats[128 + tid] * invn);
            float sc = g[tid] * rsqrtf(var + 1e-5f);
            ssl[tid] = sc;
            ssl[128 + tid] = fmaf(-mean, sc, be[tid]);
        }
        __syncthreads();
    }

    // stage Wt rows [col0, col0+64) (64 x 128)
    for (int idx = tid; idx < 64 * 16; idx += 256) {
        int r = idx >> 4;
        int c = (idx & 15) * 8;
        uint4 v = *reinterpret_cast<const uint4*>(Wt + (size_t)(col0 + r) * 128 + c);
        *reinterpret_cast<uint4*>(&Bsd[r][c]) = v;
    }
    // stage A rows (64 x 128) with optional BN+ReLU
    for (int idx = tid; idx < 64 * 16; idx += 256) {
        int r = idx >> 4;
        int c = (idx & 15) * 8;
        int grow = row0 + r;
        uint4 v = make_uint4(0u, 0u, 0u, 0u);
        if (grow < n)
            v = *reinterpret_cast<const uint4*>(A + (size_t)grow * 128 + c);
        if (BN) {
            unsigned int p[4] = {v.x, v.y, v.z, v.w};
#pragma unroll
            for (int h = 0; h < 4; ++h) {
                int f = c + h * 2;
                float lo = fmaxf(fmaf(bf2f_lo(p[h]), ssl[f], ssl[128 + f]), 0.f);
                float hi = fmaxf(fmaf(bf2f_hi(p[h]), ssl[f + 1], ssl[129 + f]), 0.f);
                p[h] = f2bf(lo) | ((unsigned)f2bf(hi) << 16);
            }
            v = make_uint4(p[0], p[1], p[2], p[3]);
        }
        *reinterpret_cast<uint4*>(&Asd[r][c]) = v;
    }
    __syncthreads();

    f32x4 acc[4];
#pragma unroll
    for (int t = 0; t < 4; ++t) acc[t] = (f32x4)(0.f);

    const int l15 = lane & 15;
    const int quad = lane >> 4;
#pragma unroll
    for (int kb = 0; kb < 128; kb += 32) {
        short8 a = *reinterpret_cast<const short8*>(&Asd[wave * 16 + l15][kb + quad * 8]);
#pragma unroll
        for (int t = 0; t < 4; ++t) {
            short8 b = *reinterpret_cast<const short8*>(&Bsd[t * 16 + l15][kb + quad * 8]);
            acc[t] = __builtin_amdgcn_mfma_f32_16x16x32_bf16(a, b, acc[t], 0, 0, 0);
        }
    }

    const int rbase = row0 + wave * 16 + quad * 4;
    float dv[4] = {0.f, 0.f, 0.f, 0.f};
    if (rbase < n) {  // dinv padded by +64 in ws
        float4 d4 = *reinterpret_cast<const float4*>(dinv + rbase);
        dv[0] = d4.x; dv[1] = d4.y; dv[2] = d4.z; dv[3] = d4.w;
    }
#pragma unroll
    for (int t = 0; t < 4; ++t) {
        int col = col0 + t * 16 + l15;
#pragma unroll
        for (int r = 0; r < 4; ++r) {
            int row = rbase + r;
            if (row < n)
                C[(size_t)row * NC + col] = f2bf(acc[t][r] * dv[r]);
        }
    }
}

// Degree-sorted 4-node gather-reduce (r11 exact config — measured best).
template <int F, bool STATS, bool OBF>
__global__ __launch_bounds__(256) void aggregate_kernel(
    const unsigned short* __restrict__ hs, const int* __restrict__ csr_src,
    const int* __restrict__ rowptr, const int* __restrict__ perm,
    const float* __restrict__ dinv, const float* __restrict__ bias,
    void* __restrict__ outp, int n, float* __restrict__ stats) {
    const int LANES = F / 4;            // 32 for F=128, 16 for F=64
    const int GROUPS = 256 / LANES;
    const int lane = threadIdx.x % LANES;
    const int grp = threadIdx.x / LANES;
    const int fq = lane * 4;
    const float4 b4 = *reinterpret_cast<const float4*>(bias + fq);
    float s[4] = {}, sq[4] = {};

    const int stride = gridDim.x * GROUPS * 4;

    for (int j0 = (blockIdx.x * GROUPS + grp) * 4; j0 < n; j0 += stride) {
        const int nv = min(4, n - j0);
        int nd[4], e[4], end[4];
        float acc[4][4] = {};
#pragma unroll
        for (int q = 0; q < 4; ++q) {
            if (q < nv) {
                int node = perm[j0 + q];
                nd[q] = node;
                e[q] = (node == 0) ? 0 : rowptr[node - 1];
                end[q] = rowptr[node];
            } else {
                nd[q] = -1; e[q] = 0; end[q] = 0;
            }
        }
#pragma unroll
        for (int q = 0; q < 4; ++q)
            if (nd[q] >= 0)
                bf4_acc(*reinterpret_cast<const uint2*>(hs + (size_t)nd[q] * F + fq), acc[q]);
        int rem = end[0] - e[0];
#pragma unroll
        for (int q = 1; q < 4; ++q)
            if (q < nv) rem = min(rem, end[q] - e[q]);
        for (; rem >= 2; rem -= 2) {
            int i0[4], i1[4];
#pragma unroll
            for (int q = 0; q < 4; ++q) {
                i0[q] = csr_src[e[q]];
                i1[q] = csr_src[e[q] + 1];
                e[q] += 2;
            }
            uint2 v0[4], v1[4];
#pragma unroll
            for (int q = 0; q < 4; ++q) {
                v0[q] = *reinterpret_cast<const uint2*>(hs + (size_t)i0[q] * F + fq);
                v1[q] = *reinterpret_cast<const uint2*>(hs + (size_t)i1[q] * F + fq);
            }
#pragma unroll
            for (int q = 0; q < 4; ++q) {
                bf4_acc(v0[q], acc[q]);
                bf4_acc(v1[q], acc[q]);
            }
        }
#pragma unroll
        for (int q = 0; q < 4; ++q) {
            for (; e[q] < end[q]; ++e[q]) {
                int s0 = csr_src[e[q]];
                bf4_acc(*reinterpret_cast<const uint2*>(hs + (size_t)s0 * F + fq), acc[q]);
            }
        }
#pragma unroll
        for (int q = 0; q < 4; ++q) {
            if (nd[q] < 0) continue;
            const float di = dinv[nd[q]];
            float y[4];
            y[0] = fmaf(di, acc[q][0], b4.x);
            y[1] = fmaf(di, acc[q][1], b4.y);
            y[2] = fmaf(di, acc[q][2], b4.z);
            y[3] = fmaf(di, acc[q][3], b4.w);
            if (OBF) {
                uint2 p;
                p.x = f2bf(y[0]) | ((unsigned)f2bf(y[1]) << 16);
                p.y = f2bf(y[2]) | ((unsigned)f2bf(y[3]) << 16);
                *reinterpret_cast<uint2*>((unsigned short*)outp + (size_t)nd[q] * F + fq) = p;
            } else {
                *reinterpret_cast<float4*>((float*)outp + (size_t)nd[q] * F + fq) =
                    make_float4(y[0], y[1], y[2], y[3]);
            }
            if (STATS) {
#pragma unroll
                for (int j = 0; j < 4; ++j) {
                    s[j] += y[j];
                    sq[j] = fmaf(y[j], y[j], sq[j]);
                }
            }
        }
    }

    if (STATS) {  // F=128 shape: LANES=32, GROUPS=8
        __shared__ float sred[32][8];
#pragma unroll
        for (int q = 0; q < 8; ++q) {
            float v = (q < 4) ? s[q] : sq[q - 4];
            sred[lane][grp] = v;
            __syncthreads();
            if (grp == 0) {
                float t = 0.f;
#pragma unroll
                for (int g = 0; g < 8; ++g) t += sred[lane][g];
                int f = fq + (q & 3);
                atomicAdd(stats + ((q < 4) ? f : 128 + f), t);
            }
            __syncthreads();
        }
    }
}

extern "C" void kernel_launch(void* const* d_in, const int* in_sizes, int n_in,
                              void* d_out, int out_size, void* d_ws,
                              size_t ws_size, hipStream_t stream) {
    const float* x   = (const float*)d_in[0];
    const int*   ei  = (const int*)d_in[1];
    const float* W1  = (const float*)d_in[2];
    const float* b1  = (const float*)d_in[3];
    const float* g1  = (const float*)d_in[4];
    const float* be1 = (const float*)d_in[5];
    const float* W2  = (const float*)d_in[6];
    const float* b2  = (const float*)d_in[7];
    const float* g2  = (const float*)d_in[8];
    const float* be2 = (const float*)d_in[9];
    const float* W3  = (const float*)d_in[10];
    const float* b3  = (const float*)d_in[11];
    float* out = (float*)d_out;

    const int n = in_sizes[0] / 128;
    const int E = in_sizes[1] / 2;
    const int* src = ei;
    const int* dst = ei + E;

    const int B = (n + 2047) / 2048;             // sort/scan chunks (25)

    float* wsf    = (float*)d_ws;
    float* stats1 = wsf;                         // 256
    float* stats2 = stats1 + 256;                // 256
    int*   deg    = (int*)(stats2 + 256);        // n
    float* dinv   = (float*)(deg + n);           // n + 64 (padded)
    int*   bh     = (int*)(dinv + n + 64);       // 64*B (<= 64*32)
    int*   bsum   = bh + 64 * 32;                // 64
    int*   rowptr = bsum + 64;                   // n+1
    int*   perm   = rowptr + (n + 1);            // n
    int*   csrsrc = perm + n;                    // E
    unsigned short* wt1 = (unsigned short*)(csrsrc + E);      // 128*128
    unsigned short* wt2 = wt1 + 128 * 128;                    // 128*128
    unsigned short* wt3 = wt2 + 128 * 128;                    // 64*128
    unsigned short* abuf = wt3 + 64 * 128;                    // n*128 bf16
    unsigned short* hsb  = abuf + (size_t)n * 128;            // n*128 bf16

    const int EB = (E + 255) / 256;
    const int total4 = n * 32;
    const int XB = (total4 + 255) / 256;

    hipMemsetAsync(wsf, 0, (size_t)(512 + n) * 4, stream);
    prep_kernel<<<EB + XB + 160, 256, 0, stream>>>(dst, E, deg, x, abuf, total4,
                                                   W1, W2, W3, wt1, wt2, wt3,
                                                   EB, XB);
    prescan_kernel<<<B, 256, 0, stream>>>(deg, n, B, dinv, bh, rowptr, bsum);
    midscan_kernel<<<1, 256, 0, stream>>>(bh, 64 * B, bsum, B);
    place_scanC_kernel<<<2 * B, 256, 0, stream>>>(deg, n, B, bh, bsum, perm, rowptr);
    csr_build_kernel<<<EB, 256, 0, stream>>>(src, dst, E, rowptr, csrsrc);

    const int gemmRows = (n + 63) / 64;
    dim3 gemmGrid128(gemmRows, 2);               // 64-col blocks
    dim3 gemmGrid64(gemmRows, 1);
    const int aggGrid = 512;                     // r11 measured-best
    const float invn = 1.0f / n;

    // ---- layer 1 ----
    gemm_mfma<128, false><<<gemmGrid128, 256, 0, stream>>>(abuf, wt1, hsb, n, nullptr, nullptr, nullptr, invn, dinv);
    aggregate_kernel<128, true, true><<<aggGrid, 256, 0, stream>>>(hsb, csrsrc, rowptr, perm, dinv, b1, abuf, n, stats1);
    // ---- layer 2 ----
    gemm_mfma<128, true><<<gemmGrid128, 256, 0, stream>>>(abuf, wt2, hsb, n, stats1, g1, be1, invn, dinv);
    aggregate_kernel<128, true, true><<<aggGrid, 256, 0, stream>>>(hsb, csrsrc, rowptr, perm, dinv, b2, abuf, n, stats2);
    // ---- layer 3 ----
    gemm_mfma<64, true><<<gemmGrid64, 256, 0, stream>>>(abuf, wt3, hsb, n, stats2, g2, be2, invn, dinv);
    aggregate_kernel<64, false, false><<<aggGrid, 256, 0, stream>>>(hsb, csrsrc, rowptr, perm, dinv, b3, out, n, nullptr);
}